// Round 1
// baseline (854.050 us; speedup 1.0000x reference)
//
#include <hip/hip_runtime.h>
#include <hip/hip_bf16.h>

// RecNN: u = relu(contents @ W_u^T + b_u); v = u[internal] @ W_hu^T (hoisted);
// 10 levels emb = relu([emb_L|emb_R] @ W_LR^T + v + b_h).
//
// Round-5 structure: 128x128 block tile (4 waves, 64x64 each), BK=32,
// THREE-slot LDS rotation with counted vmcnt + raw s_barrier (T3/T4):
// stage k+2 right after the barrier of step k, wait vmcnt(6|4) only -> the
// prefetch stays in flight across two steps instead of draining to 0 each
// step. XOR granule swizzle (source-preswizzled for linear global_load_lds,
// same XOR on ds_read) kills the 8-way bank conflict on the b128 fragment
// reads. s_setprio(1) around the MFMA cluster (T5). XCD swizzle kept.

typedef unsigned short u16;
typedef __attribute__((ext_vector_type(8))) short bf16x8;
typedef __attribute__((ext_vector_type(4))) float f32x4;

#define BK 32

__device__ __forceinline__ u16 f2b(float f) {
  union { float f; unsigned u; } c; c.f = f;
  unsigned u = c.u;
  return (u16)((u + 0x7fffu + ((u >> 16) & 1u)) >> 16);  // RNE
}

__device__ __forceinline__ float b2f(unsigned hi16) {
  union { float f; unsigned u; } c; c.u = hi16 << 16; return c.f;
}

__device__ __forceinline__ void glds16(const void* g, void* l) {
  __builtin_amdgcn_global_load_lds(
      (__attribute__((address_space(1))) void*)g,
      (__attribute__((address_space(3))) void*)l, 16, 0, 0);
}

// Counted wait + raw barrier. lgkmcnt(0) before the barrier is what makes
// stage-after-barrier race-free: every wave's ds_reads of the previous step
// are retired before anyone passes, so the slot being overwritten is dead.
// The trailing memory-clobber asm pins all memory ops below the barrier.
template <int N>
__device__ __forceinline__ void wait_barrier() {
  asm volatile("s_waitcnt vmcnt(%0) lgkmcnt(0)" :: "n"(N) : "memory");
  __builtin_amdgcn_s_barrier();
  asm volatile("" ::: "memory");
}

__device__ __forceinline__ void vm_fence() {      // vmem group boundary
  asm volatile("" ::: "memory");
}

// MODE 0: A fp32 [M][K] (reg-staged + cvt), epilogue bias+relu   (GEMM1)
// MODE 2: A bf16 [M][K], raw store                               (v-GEMM)
// MODE 1: A gathered [emb[c.x] | emb[c.y]] (K=1024), +v+bias+relu (levels)
template <int MODE>
__global__ __launch_bounds__(256, 3)
void gemm_db(const float* __restrict__ Af32,
             const u16* __restrict__ Abf,
             const u16* __restrict__ embPrev,
             const int2* __restrict__ idx,
             const u16* __restrict__ vLvl,   // [M][512] bf16
             const u16* __restrict__ W,      // bf16, row stride ldb (B^T)
             int ldb,
             const float* __restrict__ bias,
             u16* __restrict__ out,          // [M][512] bf16
             int M, int K, int nBlkM) {
  __shared__ __align__(16) u16 lA[3][128 * BK];   // 3 x 8 KB
  __shared__ __align__(16) u16 lB[3][128 * BK];   // 3 x 8 KB

  const int tid  = threadIdx.x;
  const int lane = tid & 63;
  const int wv   = tid >> 6;
  const int wrow = wv >> 1, wcol = wv & 1;

  // XCD swizzle: 4 n-blocks of one m-block -> same XCD (b%8).
  int mb, nb;
  {
    int b = blockIdx.x;
    if ((nBlkM & 7) == 0) {
      int xcd = b & 7;
      nb = (b >> 3) & 3;
      mb = ((b >> 5) << 3) | xcd;
    } else { nb = b & 3; mb = b >> 2; }
  }
  const int mBase = mb * 128;
  const int n0    = nb * 128;

  const int rowA0 = tid >> 2;       // tile row (and +64 for second glds)
  // Source-preswizzled column granule: physical granule (tid&3) of row r
  // holds logical granule (tid&3) ^ ((r>>1)&3); (r>>1)&3 == (tid>>3)&3,
  // identical for the +64 row. 8 elements = 16 B per granule.
  const int colq  = (((tid & 3) ^ ((tid >> 3) & 3))) * 8;

  const float *af0 = nullptr, *af1 = nullptr;
  const u16 *ab0 = nullptr, *ab1 = nullptr;
  const u16 *aL0 = nullptr, *aR0 = nullptr, *aL1 = nullptr, *aR1 = nullptr;
  {
    int m0 = min(mBase + rowA0, M - 1);
    int m1 = min(mBase + rowA0 + 64, M - 1);
    if (MODE == 0) {
      af0 = Af32 + (size_t)m0 * K + colq;
      af1 = Af32 + (size_t)m1 * K + colq;
    } else if (MODE == 2) {
      ab0 = Abf + (size_t)m0 * K + colq;
      ab1 = Abf + (size_t)m1 * K + colq;
    } else {
      int2 c0 = idx[m0], c1 = idx[m1];
      aL0 = embPrev + (size_t)c0.x * 512 + colq;
      aR0 = embPrev + (size_t)c0.y * 512 + colq;
      aL1 = embPrev + (size_t)c1.x * 512 + colq;
      aR1 = embPrev + (size_t)c1.y * 512 + colq;
    }
  }
  const u16* bp0 = W + (size_t)(n0 + rowA0) * ldb + colq;
  const u16* bp1 = W + (size_t)(n0 + rowA0 + 64) * ldb + colq;

  f32x4 acc[4][4] = {};
  const int fm  = lane & 15;
  // Swizzled read granule: logical g=lane>>4 lives at g ^ ((row>>1)&3) and
  // (row>>1)&3 == (fm>>1)&3. Each 8-lane batch now spans all 32 banks.
  const int gs8 = ((lane >> 4) ^ ((fm >> 1) & 3)) * 8;
  const int nk  = K / BK;

  auto stageB = [&](int buf, int k0) {
    glds16(bp0 + k0, &lB[buf][tid * 8]);
    glds16(bp1 + k0, &lB[buf][(tid + 256) * 8]);
  };
  auto stageA_bf = [&](int buf, int k0) {
    if (MODE == 2) {
      glds16(ab0 + k0, &lA[buf][tid * 8]);
      glds16(ab1 + k0, &lA[buf][(tid + 256) * 8]);
    } else {  // MODE 1 gather; colq<32 never flips the L/R select bit
      const u16* g0 = ((k0 & 512) ? aR0 : aL0) + (k0 & 511);
      const u16* g1 = ((k0 & 512) ? aR1 : aL1) + (k0 & 511);
      glds16(g0, &lA[buf][tid * 8]);
      glds16(g1, &lA[buf][(tid + 256) * 8]);
    }
  };
  auto cvtwrite = [&](int buf, float4 x, float4 y, int slot) {
    union { __hip_bfloat162 h[4]; bf16x8 v; } o;
    o.h[0] = __float22bfloat162_rn({x.x, x.y});
    o.h[1] = __float22bfloat162_rn({x.z, x.w});
    o.h[2] = __float22bfloat162_rn({y.x, y.y});
    o.h[3] = __float22bfloat162_rn({y.z, y.w});
    *(bf16x8*)&lA[buf][slot * 8] = o.v;
  };
  auto compute = [&](int buf) {
    bf16x8 av[4], bv[4];
#pragma unroll
    for (int i = 0; i < 4; i++) {
      av[i] = *(const bf16x8*)&lA[buf][(wrow * 64 + i * 16 + fm) * BK + gs8];
      bv[i] = *(const bf16x8*)&lB[buf][(wcol * 64 + i * 16 + fm) * BK + gs8];
    }
    __builtin_amdgcn_s_setprio(1);
#pragma unroll
    for (int i = 0; i < 4; i++)
#pragma unroll
      for (int j = 0; j < 4; j++)
        acc[i][j] = __builtin_amdgcn_mfma_f32_16x16x32_bf16(av[i], bv[j], acc[i][j], 0, 0, 0);
    __builtin_amdgcn_s_setprio(0);
  };

  // MODE 0 reg-staged A tile for the NEXT k-step (cvt'd one step later).
  float4 cx0, cy0, cx1, cy1;

  // --- prologue: slots 0 and 1 ---
  if (MODE == 0) {
    const float4* s0 = (const float4*)af0;
    const float4* s1 = (const float4*)af1;
    float4 a0 = s0[0], b0 = s0[1], a1 = s1[0], b1 = s1[1];
    stageB(0, 0);
    vm_fence();                       // group boundary: {f0 x4, B0 x2}
    stageB(1, BK);
    cvtwrite(0, a0, b0, tid);
    cvtwrite(0, a1, b1, tid + 256);
    const float4* t0 = (const float4*)(af0 + BK);
    const float4* t1 = (const float4*)(af1 + BK);
    cx0 = t0[0]; cy0 = t0[1]; cx1 = t1[0]; cy1 = t1[1];
  } else {
    stageA_bf(0, 0);
    stageB(0, 0);
    vm_fence();                       // group boundary: {A0 x2, B0 x2}
    stageA_bf(1, BK);
    stageB(1, BK);
  }

  // Per-step vmem group size (uniform, fence-bounded): the counted wait
  // retires everything older than the newest PEND ops == the k+1 group.
  constexpr int PEND = (MODE == 0) ? 6 : 4;

  int sl = 0;                         // LDS slot of current k-step
  int ks = 0;
  for (; ks < nk - 2; ks++) {
    wait_barrier<PEND>();             // slot ks complete in every wave
    int s1 = sl + 1; if (s1 == 3) s1 = 0;
    int s2 = s1 + 1; if (s2 == 3) s2 = 0;
    const int k2 = (ks + 2) * BK;
    if (MODE == 0) {
      stageB(s2, k2);                 // in flight for ~2 steps
      compute(sl);
      cvtwrite(s1, cx0, cy0, tid);    // f32(ks+1) -> lA slot ks+1
      cvtwrite(s1, cx1, cy1, tid + 256);
      const float4* t0 = (const float4*)(af0 + k2);
      const float4* t1 = (const float4*)(af1 + k2);
      cx0 = t0[0]; cy0 = t0[1]; cx1 = t1[0]; cy1 = t1[1];
    } else {
      stageA_bf(s2, k2);
      stageB(s2, k2);
      compute(sl);
    }
    sl = s1;
  }
  { // ks = nk-2: no more staging to issue
    wait_barrier<PEND>();
    int s1 = sl + 1; if (s1 == 3) s1 = 0;
    compute(sl);
    if (MODE == 0) {
      cvtwrite(s1, cx0, cy0, tid);
      cvtwrite(s1, cx1, cy1, tid + 256);
    }
    sl = s1;
  }
  // ks = nk-1: drain everything
  wait_barrier<0>();
  compute(sl);

  // Epilogue: C/D layout col=lane&15, row=(lane>>4)*4+reg (m89-verified).
  const int r0 = (lane >> 4) * 4;
#pragma unroll
  for (int i = 0; i < 4; i++) {
    int mI = mBase + wrow * 64 + i * 16 + r0;
#pragma unroll
    for (int j = 0; j < 4; j++) {
      int col = n0 + wcol * 64 + j * 16 + fm;
      float bb = (MODE == 2) ? 0.f : bias[col];
#pragma unroll
      for (int r = 0; r < 4; r++) {
        int m = mI + r;
        if (m < M) {
          float v = acc[i][j][r] + bb;
          if (MODE == 1) v += b2f(vLvl[(size_t)m * 512 + col]);
          if (MODE != 2) v = v > 0.f ? v : 0.f;
          out[(size_t)m * 512 + col] = f2b(v);
        }
      }
    }
  }
}

// One launch: convert W_u (512x256) and W_h (512x1536) fp32 -> bf16.
__global__ void cvt_weights(const float* __restrict__ Wu,
                            const float* __restrict__ Wh,
                            u16* __restrict__ Wub, u16* __restrict__ Whb) {
  const int nWu = 512 * 256 / 8;
  const int nWh = 512 * 1536 / 8;
  int i = blockIdx.x * blockDim.x + threadIdx.x;
  const float* src; u16* dst; int c;
  if (i < nWu) { src = Wu; dst = Wub; c = i; }
  else if (i < nWu + nWh) { src = Wh; dst = Whb; c = i - nWu; }
  else return;
  const float4* s = (const float4*)(src + (size_t)c * 8);
  float4 a = s[0], b = s[1];
  union { u16 u[8]; bf16x8 v; } o;
  o.u[0] = f2b(a.x); o.u[1] = f2b(a.y); o.u[2] = f2b(a.z); o.u[3] = f2b(a.w);
  o.u[4] = f2b(b.x); o.u[5] = f2b(b.y); o.u[6] = f2b(b.z); o.u[7] = f2b(b.w);
  *(bf16x8*)(dst + (size_t)c * 8) = o.v;
}

__global__ void cvt_bf16_to_f32(const u16* __restrict__ src, float* __restrict__ dst, int n4) {
  int i = blockIdx.x * blockDim.x + threadIdx.x;
  if (i >= n4) return;
  uint2 p = ((const uint2*)src)[i];
  float4 o;
  o.x = b2f(p.x & 0xffffu); o.y = b2f(p.x >> 16);
  o.z = b2f(p.y & 0xffffu); o.w = b2f(p.y >> 16);
  ((float4*)dst)[i] = o;
}

extern "C" void kernel_launch(void* const* d_in, const int* in_sizes, int n_in,
                              void* d_out, int out_size, void* d_ws, size_t ws_size,
                              hipStream_t stream) {
  const float* contents = (const float*)d_in[0];
  const int2*  children = (const int2*)d_in[1];
  const float* W_u = (const float*)d_in[2];
  const float* b_u = (const float*)d_in[3];
  const float* W_h = (const float*)d_in[4];
  const float* b_h = (const float*)d_in[5];
  float* out = (float*)d_out;

  const int B = 64, D = 11, F = 256, H = 512;
  const int N = B * ((1 << D) - 1);            // 131008
  const int NI = B * ((1 << (D - 1)) - 1);     // 65472

  // Workspace (u16 elems): u_bf [N*512] | v_bf [NI*512] | Wub | Whb.
  u16* ws16 = (u16*)d_ws;
  u16* u_bf = ws16;
  u16* v_bf = ws16 + (size_t)N * H;
  u16* Wub  = v_bf + (size_t)NI * H;
  u16* Whb  = Wub + 512 * 256;
  u16* embA = u_bf;                            // level-9 dst (32768 rows)
  u16* embB = u_bf + (size_t)32768 * 512;

  // --- weight conversion (single tiny launch) ---
  {
    int n = (512 * 256 + 512 * 1536) / 8;
    cvt_weights<<<(n + 255) / 256, 256, 0, stream>>>(W_u, W_h, Wub, Whb);
  }

  // --- GEMM1: u = relu(contents @ W_u^T + b_u) ---
  {
    int mb = (N + 127) / 128;                  // 1024
    gemm_db<0><<<mb * 4, 256, 0, stream>>>(contents, nullptr, nullptr, nullptr,
                                           nullptr, Wub, F, b_u, u_bf, N, F, mb);
  }

  // --- v-GEMM: v = u[0:NI] @ W_hu^T (W_h cols 1024..1535 in place) ---
  {
    int mb = (NI + 127) / 128;                 // 512
    gemm_db<2><<<mb * 4, 256, 0, stream>>>(nullptr, u_bf, nullptr, nullptr,
                                           nullptr, Whb + 1024, 3 * H, nullptr,
                                           v_bf, NI, H, mb);
  }

  // --- tree levels j = D-2 .. 0 (K=1024 children; v in epilogue) ---
  const u16* embPrev = u_bf + (size_t)NI * H;  // leaves = u[NI:]
  u16* dst = embA;
  for (int j = D - 2; j >= 0; --j) {
    int M = B << j;
    int o = B * ((1 << j) - 1);
    int mb = (M + 127) / 128;
    gemm_db<1><<<mb * 4, 256, 0, stream>>>(nullptr, nullptr, embPrev,
                                           children + o, v_bf + (size_t)o * H,
                                           Whb, 3 * H, b_h, dst, M, 2 * H, mb);
    embPrev = dst;
    dst = (dst == embA) ? embB : embA;
  }

  // --- level-0 emb (64 x 512) -> fp32 output ---
  {
    int n4 = B * H / 4;
    cvt_bf16_to_f32<<<(n4 + 255) / 256, 256, 0, stream>>>(embPrev, out, n4);
  }
}

// Round 2
// 734.996 us; speedup vs baseline: 1.1620x; 1.1620x over previous
//
#include <hip/hip_runtime.h>
#include <hip/hip_bf16.h>

// RecNN: u = relu(contents @ W_u^T + b_u); v = u[internal] @ W_hu^T (hoisted);
// 10 levels emb = relu([emb_L|emb_R] @ W_LR^T + v + b_h).
//
// Round-6 structure: 128x256 block tile, 512 threads (8 waves, 2x4 grid,
// each wave 64x64 / acc[4][4] -- identical inner structure to the proven
// round-4 kernel). Halves the A-panel L2/L3 re-read traffic (2 n-blocks per
// m-block instead of 4), which the round-4/5 counters identified as the
// bound (achieved BW pinned at ~1.7 TB/s regardless of schedule). Schedule
// is the proven round-4 two-buffer one-__syncthreads-per-step loop (the
// round-5 3-slot counted-vmcnt variant spilled MODE 0 to scratch: +216 MB
// writes). Keeps the validated XOR granule swizzle (source-preswizzled for
// linear global_load_lds, same XOR on ds_read): bank conflicts 4.19M -> 0.

typedef unsigned short u16;
typedef __attribute__((ext_vector_type(8))) short bf16x8;
typedef __attribute__((ext_vector_type(4))) float f32x4;

#define BK 32

__device__ __forceinline__ u16 f2b(float f) {
  union { float f; unsigned u; } c; c.f = f;
  unsigned u = c.u;
  return (u16)((u + 0x7fffu + ((u >> 16) & 1u)) >> 16);  // RNE
}

__device__ __forceinline__ float b2f(unsigned hi16) {
  union { float f; unsigned u; } c; c.u = hi16 << 16; return c.f;
}

__device__ __forceinline__ void glds16(const void* g, void* l) {
  __builtin_amdgcn_global_load_lds(
      (__attribute__((address_space(1))) void*)g,
      (__attribute__((address_space(3))) void*)l, 16, 0, 0);
}

// MODE 0: A fp32 [M][K] (reg-staged + cvt), epilogue bias+relu   (GEMM1)
// MODE 2: A bf16 [M][K], raw store                               (v-GEMM)
// MODE 1: A gathered [emb[c.x] | emb[c.y]] (K=1024), +v+bias+relu (levels)
template <int MODE>
__global__ __launch_bounds__(512, 2)
void gemm_db(const float* __restrict__ Af32,
             const u16* __restrict__ Abf,
             const u16* __restrict__ embPrev,
             const int2* __restrict__ idx,
             const u16* __restrict__ vLvl,   // [M][512] bf16
             const u16* __restrict__ W,      // bf16, row stride ldb (B^T)
             int ldb,
             const float* __restrict__ bias,
             u16* __restrict__ out,          // [M][512] bf16
             int M, int K, int nBlkM) {
  __shared__ __align__(16) u16 lA[2][128 * BK];   // 2 x 8 KB
  __shared__ __align__(16) u16 lB[2][256 * BK];   // 2 x 16 KB

  const int tid  = threadIdx.x;
  const int lane = tid & 63;
  const int wv   = tid >> 6;                 // 0..7
  const int wrow = wv >> 2, wcol = wv & 3;   // 2 x 4 wave grid

  // XCD swizzle: the 2 n-blocks of one m-block -> same XCD (b%8), adjacent
  // in dispatch order, so A re-reads hit that XCD's L2.
  int mb, nb;
  {
    int b = blockIdx.x;
    if ((nBlkM & 7) == 0) {
      int xcd = b & 7;
      nb = (b >> 3) & 1;
      mb = ((b >> 4) << 3) | xcd;
    } else { nb = b & 1; mb = b >> 1; }
  }
  const int mBase = mb * 128;
  const int n0    = nb * 256;

  const int rowA0 = tid >> 2;                // 0..127 (one A row / thread)
  // Source-preswizzled column granule (8 elems = one 16B glds granule):
  // physical granule (tid&3) of row r holds logical granule
  // (tid&3) ^ ((r>>1)&3); (r>>1)&3 == (tid>>3)&3.
  const int colq  = ((tid & 3) ^ ((tid >> 3) & 3)) * 8;

  const float* af0 = nullptr;
  const u16 *ab0 = nullptr, *aL0 = nullptr, *aR0 = nullptr;
  {
    int m0 = min(mBase + rowA0, M - 1);
    if (MODE == 0) {
      af0 = Af32 + (size_t)m0 * K + colq;
    } else if (MODE == 2) {
      ab0 = Abf + (size_t)m0 * K + colq;
    } else {
      int2 c0 = idx[m0];
      aL0 = embPrev + (size_t)c0.x * 512 + colq;
      aR0 = embPrev + (size_t)c0.y * 512 + colq;
    }
  }
  const u16* bp0 = W + (size_t)(n0 + rowA0) * ldb + colq;        // B rows 0..127
  const u16* bp1 = bp0 + (size_t)128 * ldb;                      // B rows 128..255

  f32x4 acc[4][4] = {};
  const int fm  = lane & 15;
  // Read-side swizzle: logical granule g=lane>>4 of row r lives at
  // g ^ ((r>>1)&3), and (r>>1)&3 == (fm>>1)&3 (row offsets are x16).
  const int gs8 = ((lane >> 4) ^ ((fm >> 1) & 3)) * 8;
  const int nk  = K / BK;

  auto stageB = [&](int buf, int k0) {
    glds16(bp0 + k0, &lB[buf][tid * 8]);
    glds16(bp1 + k0, &lB[buf][(tid + 512) * 8]);
  };
  auto stageA_bf = [&](int buf, int k0) {
    if (MODE == 2) {
      glds16(ab0 + k0, &lA[buf][tid * 8]);
    } else {  // MODE 1 gather; colq < 32 elems never flips the L/R bit
      const u16* g0 = ((k0 & 512) ? aR0 : aL0) + (k0 & 511);
      glds16(g0, &lA[buf][tid * 8]);
    }
  };
  auto cvtwrite = [&](int buf, float4 x, float4 y) {
    union { __hip_bfloat162 h[4]; bf16x8 v; } o;
    o.h[0] = __float22bfloat162_rn({x.x, x.y});
    o.h[1] = __float22bfloat162_rn({x.z, x.w});
    o.h[2] = __float22bfloat162_rn({y.x, y.y});
    o.h[3] = __float22bfloat162_rn({y.z, y.w});
    *(bf16x8*)&lA[buf][tid * 8] = o.v;
  };

  // --- prologue: stage k-step 0 into buffer 0 ---
  if (MODE == 0) {
    const float4* s0 = (const float4*)af0;
    cvtwrite(0, s0[0], s0[1]);
    stageB(0, 0);
  } else {
    stageA_bf(0, 0);
    stageB(0, 0);
  }

  for (int ks = 0; ks < nk; ks++) {
    const int cur = ks & 1, nxt = cur ^ 1;
    __syncthreads();                 // cur buffer complete (vmcnt+lgkm drained)
    const bool more = (ks + 1 < nk);
    float4 x0, y0;
    if (more) {
      const int k1 = (ks + 1) * BK;
      if (MODE == 0) {               // issue loads now, convert after MFMA
        const float4* s0 = (const float4*)(af0 + k1);
        x0 = s0[0]; y0 = s0[1];
      } else {
        stageA_bf(nxt, k1);
      }
      stageB(nxt, k1);               // in flight during the MFMA stage below
    }

    bf16x8 av[4], bv[4];
#pragma unroll
    for (int i = 0; i < 4; i++) {
      av[i] = *(const bf16x8*)&lA[cur][(wrow * 64 + i * 16 + fm) * BK + gs8];
      bv[i] = *(const bf16x8*)&lB[cur][(wcol * 64 + i * 16 + fm) * BK + gs8];
    }
#pragma unroll
    for (int i = 0; i < 4; i++)
#pragma unroll
      for (int j = 0; j < 4; j++)
        acc[i][j] = __builtin_amdgcn_mfma_f32_16x16x32_bf16(av[i], bv[j], acc[i][j], 0, 0, 0);

    if (MODE == 0 && more) {         // convert + LDS-write after MFMA issued
      cvtwrite(nxt, x0, y0);
    }
  }

  // Epilogue: C/D layout col=lane&15, row=(lane>>4)*4+reg (m89-verified).
  const int r0 = (lane >> 4) * 4;
#pragma unroll
  for (int i = 0; i < 4; i++) {
    int mI = mBase + wrow * 64 + i * 16 + r0;
#pragma unroll
    for (int j = 0; j < 4; j++) {
      int col = n0 + wcol * 64 + j * 16 + fm;
      float bb = (MODE == 2) ? 0.f : bias[col];
#pragma unroll
      for (int r = 0; r < 4; r++) {
        int m = mI + r;
        if (m < M) {
          float v = acc[i][j][r] + bb;
          if (MODE == 1) v += b2f(vLvl[(size_t)m * 512 + col]);
          if (MODE != 2) v = v > 0.f ? v : 0.f;
          out[(size_t)m * 512 + col] = f2b(v);
        }
      }
    }
  }
}

// One launch: convert W_u (512x256) and W_h (512x1536) fp32 -> bf16.
__global__ void cvt_weights(const float* __restrict__ Wu,
                            const float* __restrict__ Wh,
                            u16* __restrict__ Wub, u16* __restrict__ Whb) {
  const int nWu = 512 * 256 / 8;
  const int nWh = 512 * 1536 / 8;
  int i = blockIdx.x * blockDim.x + threadIdx.x;
  const float* src; u16* dst; int c;
  if (i < nWu) { src = Wu; dst = Wub; c = i; }
  else if (i < nWu + nWh) { src = Wh; dst = Whb; c = i - nWu; }
  else return;
  const float4* s = (const float4*)(src + (size_t)c * 8);
  float4 a = s[0], b = s[1];
  union { u16 u[8]; bf16x8 v; } o;
  o.u[0] = f2b(a.x); o.u[1] = f2b(a.y); o.u[2] = f2b(a.z); o.u[3] = f2b(a.w);
  o.u[4] = f2b(b.x); o.u[5] = f2b(b.y); o.u[6] = f2b(b.z); o.u[7] = f2b(b.w);
  *(bf16x8*)(dst + (size_t)c * 8) = o.v;
}

__global__ void cvt_bf16_to_f32(const u16* __restrict__ src, float* __restrict__ dst, int n4) {
  int i = blockIdx.x * blockDim.x + threadIdx.x;
  if (i >= n4) return;
  uint2 p = ((const uint2*)src)[i];
  float4 o;
  o.x = b2f(p.x & 0xffffu); o.y = b2f(p.x >> 16);
  o.z = b2f(p.y & 0xffffu); o.w = b2f(p.y >> 16);
  ((float4*)dst)[i] = o;
}

extern "C" void kernel_launch(void* const* d_in, const int* in_sizes, int n_in,
                              void* d_out, int out_size, void* d_ws, size_t ws_size,
                              hipStream_t stream) {
  const float* contents = (const float*)d_in[0];
  const int2*  children = (const int2*)d_in[1];
  const float* W_u = (const float*)d_in[2];
  const float* b_u = (const float*)d_in[3];
  const float* W_h = (const float*)d_in[4];
  const float* b_h = (const float*)d_in[5];
  float* out = (float*)d_out;

  const int B = 64, D = 11, F = 256, H = 512;
  const int N = B * ((1 << D) - 1);            // 131008
  const int NI = B * ((1 << (D - 1)) - 1);     // 65472

  // Workspace (u16 elems): u_bf [N*512] | v_bf [NI*512] | Wub | Whb.
  u16* ws16 = (u16*)d_ws;
  u16* u_bf = ws16;
  u16* v_bf = ws16 + (size_t)N * H;
  u16* Wub  = v_bf + (size_t)NI * H;
  u16* Whb  = Wub + 512 * 256;
  u16* embA = u_bf;                            // level-9 dst (32768 rows)
  u16* embB = u_bf + (size_t)32768 * 512;

  // --- weight conversion (single tiny launch) ---
  {
    int n = (512 * 256 + 512 * 1536) / 8;
    cvt_weights<<<(n + 255) / 256, 256, 0, stream>>>(W_u, W_h, Wub, Whb);
  }

  // --- GEMM1: u = relu(contents @ W_u^T + b_u) ---
  {
    int mb = (N + 127) / 128;                  // 1024
    gemm_db<0><<<mb * 2, 512, 0, stream>>>(contents, nullptr, nullptr, nullptr,
                                           nullptr, Wub, F, b_u, u_bf, N, F, mb);
  }

  // --- v-GEMM: v = u[0:NI] @ W_hu^T (W_h cols 1024..1535 in place) ---
  {
    int mb = (NI + 127) / 128;                 // 512
    gemm_db<2><<<mb * 2, 512, 0, stream>>>(nullptr, u_bf, nullptr, nullptr,
                                           nullptr, Whb + 1024, 3 * H, nullptr,
                                           v_bf, NI, H, mb);
  }

  // --- tree levels j = D-2 .. 0 (K=1024 children; v in epilogue) ---
  const u16* embPrev = u_bf + (size_t)NI * H;  // leaves = u[NI:]
  u16* dst = embA;
  for (int j = D - 2; j >= 0; --j) {
    int M = B << j;
    int o = B * ((1 << j) - 1);
    int mb = (M + 127) / 128;
    gemm_db<1><<<mb * 2, 512, 0, stream>>>(nullptr, nullptr, embPrev,
                                           children + o, v_bf + (size_t)o * H,
                                           Whb, 3 * H, b_h, dst, M, 2 * H, mb);
    embPrev = dst;
    dst = (dst == embA) ? embB : embA;
  }

  // --- level-0 emb (64 x 512) -> fp32 output ---
  {
    int n4 = B * H / 4;
    cvt_bf16_to_f32<<<(n4 + 255) / 256, 256, 0, stream>>>(embPrev, out, n4);
  }
}